// Round 1
// baseline (11.338 us; speedup 1.0000x reference)
//
#include <hip/hip_runtime.h>

// Ml4fTransformer_48421461295652
//
// Algebraic collapse: DD == 1, so every decoder LayerNorm normalizes over a
// single element -> (x - mean) == 0 exactly -> output == bias exactly.
// The final dec_out = layer_norm(d, dec_norm_g, dec_norm_b) therefore equals
// dec_norm_b[0] everywhere, independent of d (and hence independent of the
// entire encoder, the learn projection, and all decoder layers).
//
// Output:  out[b, j] = relu( dec_norm_b[0] * sum_i map_w[i][j] + map_b[j] )
// for b in [0,16), j in [0,64).  map_w is row-major [64][64].
//
// One block, 64 threads (one wave). Thread j owns output column j:
// column-sum of map_w (stride-64 reads across 64 rows; each row's 64 floats
// are one fully-coalesced 256B line for the wave), then broadcast-store to
// the 16 batch rows.

#define B_    16
#define PRED_ 64

__global__ __launch_bounds__(64)
void ml4f_collapsed_kernel(const float* __restrict__ dec_norm_b,
                           const float* __restrict__ map_w,
                           const float* __restrict__ map_b,
                           float* __restrict__ out) {
    const int j = threadIdx.x;          // 0..63, one output column per lane
    const float c = dec_norm_b[0];

    float s = 0.0f;
    #pragma unroll
    for (int i = 0; i < PRED_; ++i) {
        // lane j reads map_w[i][j]: wave's 64 lanes cover one contiguous row
        s = fmaf(c, map_w[i * PRED_ + j], s);
    }
    float v = s + map_b[j];
    v = v > 0.0f ? v : 0.0f;            // ReLU

    #pragma unroll
    for (int b = 0; b < B_; ++b) {
        out[b * PRED_ + j] = v;         // identical row for every batch
    }
}

extern "C" void kernel_launch(void* const* d_in, const int* in_sizes, int n_in,
                              void* d_out, int out_size, void* d_ws, size_t ws_size,
                              hipStream_t stream) {
    // setup_inputs() order: ... dec_norm_g=39, dec_norm_b=40, map_w=41, map_b=42
    const float* dec_norm_b = (const float*)d_in[40];  // (1,)
    const float* map_w      = (const float*)d_in[41];  // (64, 64) row-major
    const float* map_b      = (const float*)d_in[42];  // (64,)
    float* out = (float*)d_out;                        // (16, 64) fp32

    ml4f_collapsed_kernel<<<1, 64, 0, stream>>>(dec_norm_b, map_w, map_b, out);
}